// Round 5
// baseline (460.046 us; speedup 1.0000x reference)
//
#include <hip/hip_runtime.h>
#include <hip/hip_bf16.h>
#include <stdint.h>

typedef int v4i __attribute__((ext_vector_type(4)));
typedef float v4f __attribute__((ext_vector_type(4)));

#define T_TOKENS 8192
#define KDIM 4096
#define NDIM 4096

#define BM 128
#define BN 128
#define BK 64

// ---------------------------------------------------------------------------
// Kernel 1: repack weight int32 -> int8 (harness widens integer inputs).
// ---------------------------------------------------------------------------
__global__ __launch_bounds__(256) void conv_w(const int* __restrict__ w32,
                                              int8_t* __restrict__ w8) {
    int idx = blockIdx.x * 256 + threadIdx.x;          // 0 .. 4096*4096/16-1
    const v4i* src = (const v4i*)w32 + (size_t)idx * 4;
    v4i p;
#pragma unroll
    for (int q = 0; q < 4; ++q) {
        v4i s = src[q];
        p[q] = (s[0] & 255) | ((s[1] & 255) << 8) | ((s[2] & 255) << 16)
             | ((s[3] & 255) << 24);
    }
    ((v4i*)w8)[idx] = p;
}

// ---------------------------------------------------------------------------
// Kernel 2: per-token dynamic quantization (x is fp32: fp16 promoted by the
// harness). One block per token row of 4096. Exact IEEE ops to match ref:
// sc = max|x|/127 (fp32 div), q = rint(x/sc) (half-to-even), clip.
// ---------------------------------------------------------------------------
__global__ __launch_bounds__(256) void quant_x(const float* __restrict__ x,
                                               int8_t* __restrict__ qx,
                                               float* __restrict__ xs) {
    int t = blockIdx.x;
    int tid = threadIdx.x;
    const v4f* xrow = (const v4f*)(x + (size_t)t * KDIM);

    v4f vals[4];
    float m = 0.f;
#pragma unroll
    for (int q = 0; q < 4; ++q) {
        v4f v = xrow[q * 256 + tid];
        vals[q] = v;
        m = fmaxf(m, fmaxf(fmaxf(fabsf(v[0]), fabsf(v[1])),
                           fmaxf(fabsf(v[2]), fabsf(v[3]))));
    }
#pragma unroll
    for (int off = 32; off > 0; off >>= 1)
        m = fmaxf(m, __shfl_xor(m, off));

    __shared__ float wmax[4];
    __shared__ float sh_scale;
    int wave = tid >> 6;
    if ((tid & 63) == 0) wmax[wave] = m;
    __syncthreads();
    if (tid == 0) {
        float mm = fmaxf(fmaxf(wmax[0], wmax[1]), fmaxf(wmax[2], wmax[3]));
        float sc = mm / 127.0f;
        sh_scale = sc;
        xs[t] = sc;
    }
    __syncthreads();
    float sc = sh_scale;

    unsigned int* qrow = (unsigned int*)(qx + (size_t)t * KDIM);
#pragma unroll
    for (int q = 0; q < 4; ++q) {
        unsigned int packed = 0;
#pragma unroll
        for (int j = 0; j < 4; ++j) {
            float fq = rintf(vals[q][j] / sc);
            fq = fminf(fmaxf(fq, -128.f), 127.f);
            int b = (int)fq;
            packed |= ((unsigned int)(unsigned char)(b & 0xff)) << (8 * j);
        }
        qrow[q * 256 + tid] = packed;
    }
}

// ---------------------------------------------------------------------------
// Kernel 3: int8 GEMM, C[8192,4096] = qx[8192,4096] . W[4096,4096]^T
// 128x128 tile, BK=64, 4 waves (2x2), mfma_i32_16x16x64_i8.
// global_load_lds width-16 staging, linear LDS dest; 16B-slot XOR swizzle
// (slot ^= (row>>1)&3) applied on the GLOBAL source and the ds_read addr
// (both-sides rule #21). Verified: produces results identical to the
// direct-from-global round-3 kernel (absmax matched exactly).
// Fused dequant + bias epilogue -> FP32 output (fp16-ref => d_out is float*).
// ---------------------------------------------------------------------------
__global__ __launch_bounds__(256) void gemm_i8(
        const int8_t* __restrict__ A, const int8_t* __restrict__ B,
        const float* __restrict__ xs, const float* __restrict__ wscale,
        const float* __restrict__ bias, float* __restrict__ out) {
    __shared__ char As[BM * BK];
    __shared__ char Bs[BN * BK];

    int tid = threadIdx.x;
    int lane = tid & 63;
    int wave = tid >> 6;
    int wr = wave >> 1, wc = wave & 1;
    int bm = blockIdx.x, bn = blockIdx.y;
    int lrow = lane & 15, kg = lane >> 4;

    const int8_t* Abase = A + (size_t)bm * BM * KDIM;
    const int8_t* Bbase = B + (size_t)bn * BN * KDIM;

    v4i acc[4][4] = {};

    for (int kt = 0; kt < KDIM / BK; ++kt) {
        int k0 = kt * BK;
        // ---- stage A and B tiles (128 rows x 64B each) ----
#pragma unroll
        for (int it = 0; it < 2; ++it) {
            int idx = it * 256 + tid;          // 0..511 -> 16B chunk id
            int row = idx >> 2;                // 4 chunks per 64B row
            int slot = idx & 3;
            int gcol = (slot ^ ((row >> 1) & 3)) << 4;   // pre-swizzled source
            const int8_t* ga = Abase + (size_t)row * KDIM + k0 + gcol;
            const int8_t* gb = Bbase + (size_t)row * KDIM + k0 + gcol;
            // wave-uniform LDS base; lanes fill base + lane*16 linearly
            char* la = As + (size_t)(it * 256 + wave * 64) * 16;
            char* lb = Bs + (size_t)(it * 256 + wave * 64) * 16;
            __builtin_amdgcn_global_load_lds(
                (const __attribute__((address_space(1))) void*)ga,
                (__attribute__((address_space(3))) void*)la, 16, 0, 0);
            __builtin_amdgcn_global_load_lds(
                (const __attribute__((address_space(1))) void*)gb,
                (__attribute__((address_space(3))) void*)lb, 16, 0, 0);
        }
        __syncthreads();   // compiler drains vmcnt before s_barrier

        // ---- fragments + MFMA ----
        v4i af[4], bfr[4];
#pragma unroll
        for (int mm = 0; mm < 4; ++mm) {
            int r = wr * 64 + mm * 16 + lrow;
            int addr = r * BK + ((kg ^ ((r >> 1) & 3)) << 4);  // swizzled read
            af[mm] = *(const v4i*)(As + addr);
        }
#pragma unroll
        for (int nn = 0; nn < 4; ++nn) {
            int r = wc * 64 + nn * 16 + lrow;
            int addr = r * BK + ((kg ^ ((r >> 1) & 3)) << 4);
            bfr[nn] = *(const v4i*)(Bs + addr);
        }
#pragma unroll
        for (int mm = 0; mm < 4; ++mm)
#pragma unroll
            for (int nn = 0; nn < 4; ++nn)
                acc[mm][nn] = __builtin_amdgcn_mfma_i32_16x16x64_i8(
                    af[mm], bfr[nn], acc[mm][nn], 0, 0, 0);
        __syncthreads();
    }

    // ---- epilogue: dequant + bias, FP32 output ----
    int rowg0 = bm * BM + wr * 64;
    int colg0 = bn * BN + wc * 64;
    float xsv[4][4];
#pragma unroll
    for (int mm = 0; mm < 4; ++mm)
#pragma unroll
        for (int j = 0; j < 4; ++j)
            xsv[mm][j] = xs[rowg0 + mm * 16 + kg * 4 + j];

#pragma unroll
    for (int nn = 0; nn < 4; ++nn) {
        int col = colg0 + nn * 16 + lrow;
        float wsc = wscale[col];
        float bs = bias[col];
#pragma unroll
        for (int mm = 0; mm < 4; ++mm) {
#pragma unroll
            for (int j = 0; j < 4; ++j) {
                int row = rowg0 + mm * 16 + kg * 4 + j;
                float y = (float)acc[mm][nn][j] * wsc * xsv[mm][j] + bs;
                out[(size_t)row * NDIM + col] = y;
            }
        }
    }
}

// ---------------------------------------------------------------------------
extern "C" void kernel_launch(void* const* d_in, const int* in_sizes, int n_in,
                              void* d_out, int out_size, void* d_ws, size_t ws_size,
                              hipStream_t stream) {
    const float* x    = (const float*)d_in[0];     // fp16 promoted to fp32
    const int*   w32  = (const int*)d_in[1];       // int8 widened to int32
    const float* wsc  = (const float*)d_in[2];     // fp16 promoted to fp32
    const float* bias = (const float*)d_in[3];     // fp16 promoted to fp32
    float* out = (float*)d_out;                    // fp16-ref output => float*

    // ws layout: [qx: 8192*4096 i8][w8: 4096*4096 i8][xs: 8192 f32]
    int8_t* qx = (int8_t*)d_ws;
    int8_t* w8 = (int8_t*)d_ws + (size_t)T_TOKENS * KDIM;
    float*  xs = (float*)((int8_t*)d_ws + (size_t)T_TOKENS * KDIM + (size_t)NDIM * KDIM);

    hipLaunchKernelGGL(conv_w, dim3(NDIM * KDIM / 16 / 256), dim3(256), 0, stream, w32, w8);
    hipLaunchKernelGGL(quant_x, dim3(T_TOKENS), dim3(256), 0, stream, x, qx, xs);
    hipLaunchKernelGGL(gemm_i8, dim3(T_TOKENS / BM, NDIM / BN), dim3(256), 0, stream,
                       qx, w8, xs, wsc, bias, out);
}

// Round 6
// 393.071 us; speedup vs baseline: 1.1704x; 1.1704x over previous
//
#include <hip/hip_runtime.h>
#include <hip/hip_bf16.h>
#include <stdint.h>

typedef int v4i __attribute__((ext_vector_type(4)));
typedef float v4f __attribute__((ext_vector_type(4)));

#define T_TOKENS 8192
#define KDIM 4096
#define NDIM 4096

#define BM 256
#define BN 256
#define BKB 128   // K-bytes per LDS tile = 2 MFMA k-steps (mfma_i32_16x16x64_i8)

// ---------------------------------------------------------------------------
// Kernel 1: repack weight int32 -> int8 (harness widens integer inputs).
// ---------------------------------------------------------------------------
__global__ __launch_bounds__(256) void conv_w(const int* __restrict__ w32,
                                              int8_t* __restrict__ w8) {
    int idx = blockIdx.x * 256 + threadIdx.x;
    const v4i* src = (const v4i*)w32 + (size_t)idx * 4;
    v4i p;
#pragma unroll
    for (int q = 0; q < 4; ++q) {
        v4i s = src[q];
        p[q] = (s[0] & 255) | ((s[1] & 255) << 8) | ((s[2] & 255) << 16)
             | ((s[3] & 255) << 24);
    }
    ((v4i*)w8)[idx] = p;
}

// ---------------------------------------------------------------------------
// Kernel 2: per-token dynamic quantization (verified round 5).
// ---------------------------------------------------------------------------
__global__ __launch_bounds__(256) void quant_x(const float* __restrict__ x,
                                               int8_t* __restrict__ qx,
                                               float* __restrict__ xs) {
    int t = blockIdx.x;
    int tid = threadIdx.x;
    const v4f* xrow = (const v4f*)(x + (size_t)t * KDIM);

    v4f vals[4];
    float m = 0.f;
#pragma unroll
    for (int q = 0; q < 4; ++q) {
        v4f v = xrow[q * 256 + tid];
        vals[q] = v;
        m = fmaxf(m, fmaxf(fmaxf(fabsf(v[0]), fabsf(v[1])),
                           fmaxf(fabsf(v[2]), fabsf(v[3]))));
    }
#pragma unroll
    for (int off = 32; off > 0; off >>= 1)
        m = fmaxf(m, __shfl_xor(m, off));

    __shared__ float wmax[4];
    __shared__ float sh_scale;
    int wave = tid >> 6;
    if ((tid & 63) == 0) wmax[wave] = m;
    __syncthreads();
    if (tid == 0) {
        float mm = fmaxf(fmaxf(wmax[0], wmax[1]), fmaxf(wmax[2], wmax[3]));
        float sc = mm / 127.0f;
        sh_scale = sc;
        xs[t] = sc;
    }
    __syncthreads();
    float sc = sh_scale;

    unsigned int* qrow = (unsigned int*)(qx + (size_t)t * KDIM);
#pragma unroll
    for (int q = 0; q < 4; ++q) {
        unsigned int packed = 0;
#pragma unroll
        for (int j = 0; j < 4; ++j) {
            float fq = rintf(vals[q][j] / sc);
            fq = fminf(fmaxf(fq, -128.f), 127.f);
            int b = (int)fq;
            packed |= ((unsigned int)(unsigned char)(b & 0xff)) << (8 * j);
        }
        qrow[q * 256 + tid] = packed;
    }
}

// ---------------------------------------------------------------------------
// Kernel 3: int8 GEMM, 256x256 tile, counted-vmcnt pipelined (T2+T3+T4+T5).
// LDS 128KB = 2 bufs x [Ak0|Ak1|Bk0|Bk1] 16KB k-half panels.
// Per tile: 2 groups; each: STAGE next-tile matching k-half chunks (other
// buffer), 12 ds_read_b128, setprio+32 MFMA, vmcnt(4) (counted, never 0),
// s_barrier. Chunks land ~2 groups after issue -> HBM latency covered.
// Swizzle: slot' = kg ^ ((row>>1)&3) in 64B rows, applied on global source
// AND ds_read (both-sides, rule 21) -> 2-way bank access (free).
// ---------------------------------------------------------------------------
__global__ __launch_bounds__(512, 2) void gemm_i8(
        const int8_t* __restrict__ A, const int8_t* __restrict__ B,
        const float* __restrict__ xs, const float* __restrict__ wscale,
        const float* __restrict__ bias, float* __restrict__ out) {
    __shared__ char lds[131072];   // 2 x 64KB

    const int tid  = threadIdx.x;
    const int lane = tid & 63;
    const int w    = tid >> 6;          // wave 0..7
    const int wr   = w >> 2;            // 0..1 (M)
    const int wc   = w & 3;             // 0..3 (N)
    const int lrow = lane & 15;
    const int kg   = lane >> 4;
    const int swz  = (kg ^ ((lrow >> 1) & 3)) << 4;   // read-side swizzle

    // XCD-aware bijective swizzle: 512 blocks, 8 XCDs, 64 per XCD
    int flat = blockIdx.x;
    int f2 = (flat & 7) * 64 + (flat >> 3);
    int bm = f2 >> 4, bn = f2 & 15;     // 32 x 16

    const int8_t* Ab = A + (size_t)bm * BM * KDIM;
    const int8_t* Bb = B + (size_t)bn * BN * KDIM;

    // staging: wave w covers rows w*32 + it*16 + (lane>>2); slot = lane&3,
    // pre-swizzled source slot = (lane&3) ^ ((lane>>3)&3)  [= slot^((row>>1)&3)]
    const int srow = (w << 5) + (lane >> 2);
    const int sg16 = (((lane & 3) ^ ((lane >> 3) & 3)) << 4);
    const size_t goff = (size_t)srow * KDIM + sg16;

#define STAGE(gp, kbyte, lbase)                                                  \
    do {                                                                         \
        const int8_t* g0 = (gp) + goff + (kbyte);                                \
        char* l0 = (lbase) + (w << 11);                                          \
        __builtin_amdgcn_global_load_lds(                                        \
            (const __attribute__((address_space(1))) void*)g0,                   \
            (__attribute__((address_space(3))) void*)l0, 16, 0, 0);              \
        __builtin_amdgcn_global_load_lds(                                        \
            (const __attribute__((address_space(1))) void*)(g0 + (size_t)16 * KDIM), \
            (__attribute__((address_space(3))) void*)(l0 + 1024), 16, 0, 0);     \
    } while (0)

    v4i acc[8][4] = {};

    // ---- prologue: stage tile 0 fully, drain once (cold) ----
    STAGE(Ab, 0,  lds + 0);
    STAGE(Bb, 0,  lds + 32768);
    STAGE(Ab, 64, lds + 16384);
    STAGE(Bb, 64, lds + 49152);
    asm volatile("s_waitcnt vmcnt(0)" ::: "memory");
    __builtin_amdgcn_s_barrier();
    asm volatile("" ::: "memory");

    const int abase = wr * 128 + lrow;   // A frag row base (+m*16)
    const int bbase = wc * 64 + lrow;    // B frag row base (+n*16)

    for (int t = 0; t < KDIM / BKB; ++t) {
        char* cur = lds + ((t & 1) << 16);
        char* nxt = lds + (((t + 1) & 1) << 16);
        int   nk  = ((t + 1) & 31) * BKB;

#pragma unroll
        for (int ks = 0; ks < 2; ++ks) {
            // stage next tile's matching k-half chunks (other buffer)
            STAGE(Ab, nk + ks * 64, nxt + ks * 16384);
            STAGE(Bb, nk + ks * 64, nxt + 32768 + ks * 16384);

            const char* ap = cur + ks * 16384;
            const char* bp = cur + 32768 + ks * 16384;
            v4i af[8], bf[4];
#pragma unroll
            for (int m = 0; m < 8; ++m)
                af[m] = *(const v4i*)(ap + (abase + m * 16) * 64 + swz);
#pragma unroll
            for (int n = 0; n < 4; ++n)
                bf[n] = *(const v4i*)(bp + (bbase + n * 16) * 64 + swz);

            __builtin_amdgcn_s_setprio(1);
#pragma unroll
            for (int m = 0; m < 8; ++m)
#pragma unroll
                for (int n = 0; n < 4; ++n)
                    acc[m][n] = __builtin_amdgcn_mfma_i32_16x16x64_i8(
                        af[m], bf[n], acc[m][n], 0, 0, 0);
            __builtin_amdgcn_s_setprio(0);

            // counted wait: 4 loads (this group's stages) may stay in flight
            asm volatile("s_waitcnt vmcnt(4)" ::: "memory");
            __builtin_amdgcn_s_barrier();
            asm volatile("" ::: "memory");
        }
    }

    // ---- epilogue: dequant + bias, FP32 output ----
    int rowg0 = bm * BM + wr * 128;
    int colg0 = bn * BN + wc * 64;
    float xsv[8][4];
#pragma unroll
    for (int m = 0; m < 8; ++m)
#pragma unroll
        for (int j = 0; j < 4; ++j)
            xsv[m][j] = xs[rowg0 + m * 16 + kg * 4 + j];

#pragma unroll
    for (int n = 0; n < 4; ++n) {
        int col = colg0 + n * 16 + lrow;
        float wsc = wscale[col];
        float bs  = bias[col];
#pragma unroll
        for (int m = 0; m < 8; ++m) {
#pragma unroll
            for (int j = 0; j < 4; ++j) {
                int row = rowg0 + m * 16 + kg * 4 + j;
                float y = (float)acc[m][n][j] * wsc * xsv[m][j] + bs;
                out[(size_t)row * NDIM + col] = y;
            }
        }
    }
#undef STAGE
}

// ---------------------------------------------------------------------------
extern "C" void kernel_launch(void* const* d_in, const int* in_sizes, int n_in,
                              void* d_out, int out_size, void* d_ws, size_t ws_size,
                              hipStream_t stream) {
    const float* x    = (const float*)d_in[0];     // fp16 promoted to fp32
    const int*   w32  = (const int*)d_in[1];       // int8 widened to int32
    const float* wsc  = (const float*)d_in[2];
    const float* bias = (const float*)d_in[3];
    float* out = (float*)d_out;

    int8_t* qx = (int8_t*)d_ws;
    int8_t* w8 = (int8_t*)d_ws + (size_t)T_TOKENS * KDIM;
    float*  xs = (float*)((int8_t*)d_ws + (size_t)T_TOKENS * KDIM + (size_t)NDIM * KDIM);

    hipLaunchKernelGGL(conv_w, dim3(NDIM * KDIM / 16 / 256), dim3(256), 0, stream, w32, w8);
    hipLaunchKernelGGL(quant_x, dim3(T_TOKENS), dim3(256), 0, stream, x, qx, xs);
    hipLaunchKernelGGL(gemm_i8, dim3((T_TOKENS / BM) * (NDIM / BN)), dim3(512), 0, stream,
                       qx, w8, xs, wsc, bias, out);
}